// Round 2
// baseline (557.782 us; speedup 1.0000x reference)
//
#include <hip/hip_runtime.h>

#define N_NODES 50000

// ---------------- degree / CSR construction ----------------

__global__ void count_kernel(const int* __restrict__ ei, int* __restrict__ degi, int E){
  int e = blockIdx.x * blockDim.x + threadIdx.x;
  if(e < E){
    int d = ei[(size_t)E + e];
    atomicAdd(&degi[d], 1);
  }
}

__global__ void dis_kernel(const int* __restrict__ degi, float* __restrict__ dis, int n){
  int i = blockIdx.x * blockDim.x + threadIdx.x;
  if(i < n) dis[i] = rsqrtf((float)(degi[i] + 1));   // +1 self-loop; deg>0 always
}

__global__ __launch_bounds__(1024) void scan_kernel(const int* __restrict__ cnt,
                                                    int* __restrict__ row_ptr, int n){
  __shared__ int sdata[1024];
  __shared__ int carry;
  int tid = threadIdx.x;
  if(tid == 0) carry = 0;
  __syncthreads();
  for(int base = 0; base < n; base += 1024){
    int i = base + tid;
    int v = (i < n) ? cnt[i] : 0;
    sdata[tid] = v;
    __syncthreads();
    for(int off = 1; off < 1024; off <<= 1){
      int t = (tid >= off) ? sdata[tid - off] : 0;
      __syncthreads();
      if(tid >= off) sdata[tid] += t;
      __syncthreads();
    }
    if(i < n) row_ptr[i] = carry + sdata[tid] - v;   // exclusive prefix
    __syncthreads();
    if(tid == 0) carry += sdata[1023];
    __syncthreads();
  }
  if(tid == 0) row_ptr[n] = carry;
}

__global__ void scatter_kernel(const int* __restrict__ ei, int* __restrict__ woff,
                               const int* __restrict__ rowp, int* __restrict__ esrc, int E){
  int e = blockIdx.x * blockDim.x + threadIdx.x;
  if(e >= E) return;
  int s = ei[e];
  int d = ei[(size_t)E + e];
  int p = atomicAdd(&woff[d], 1);
  esrc[rowp[d] + p] = s;
}

// ---------------- fp32 tiled GEMM, fused epilogue ----------------
// C[M][Nc] = A[M][K] @ B[K][Nc]; SCALE: C *= dis[row]; BIAS: C += bias[col].
template<bool SCALE, bool BIAS>
__global__ __launch_bounds__(256) void gemm_kernel(const float* __restrict__ A,
    const float* __restrict__ B, float* __restrict__ C,
    const float* __restrict__ dis, const float* __restrict__ bias,
    int M, int K, int Nc){
  constexpr int BM = 64, BN = 64, BK = 16;
  __shared__ float As[BK][BM + 4];
  __shared__ float Bs[BK][BN + 4];
  int tid = threadIdx.x;
  int tx = tid & 15;
  int ty = tid >> 4;
  int row0 = blockIdx.x * BM;
  int col0 = blockIdx.y * BN;
  int ar  = tid >> 2;          // 0..63 row within A tile
  int ak  = (tid & 3) * 4;     // float4 along K
  int bkr = tid >> 4;          // 0..15 k within B tile
  int bc  = (tid & 15) * 4;    // float4 along N
  float acc[4][4] = {};
  for(int k0 = 0; k0 < K; k0 += BK){
    int arow = row0 + ar;
    float4 av = make_float4(0.f, 0.f, 0.f, 0.f);
    if(arow < M) av = *(const float4*)(A + (size_t)arow * K + k0 + ak);
    As[ak + 0][ar] = av.x; As[ak + 1][ar] = av.y;
    As[ak + 2][ar] = av.z; As[ak + 3][ar] = av.w;
    float4 bv = *(const float4*)(B + (size_t)(k0 + bkr) * Nc + col0 + bc);
    *(float4*)&Bs[bkr][bc] = bv;
    __syncthreads();
    #pragma unroll
    for(int kk = 0; kk < BK; kk++){
      float a[4], b[4];
      #pragma unroll
      for(int i = 0; i < 4; i++) a[i] = As[kk][ty * 4 + i];
      #pragma unroll
      for(int j = 0; j < 4; j++) b[j] = Bs[kk][tx * 4 + j];
      #pragma unroll
      for(int i = 0; i < 4; i++)
        #pragma unroll
        for(int j = 0; j < 4; j++)
          acc[i][j] = fmaf(a[i], b[j], acc[i][j]);
    }
    __syncthreads();
  }
  #pragma unroll
  for(int i = 0; i < 4; i++){
    int r = row0 + ty * 4 + i;
    if(r >= M) continue;
    float s = SCALE ? dis[r] : 1.0f;
    #pragma unroll
    for(int j = 0; j < 4; j++){
      int c = col0 + tx * 4 + j;
      float v = acc[i][j] * s;
      if(BIAS) v += bias[c];
      C[(size_t)r * Nc + c] = v;
    }
  }
}

// ---------------- wave-per-node gather-sum aggregation ----------------
// out[i] = relu(dis[i] * (sum_{e: dst==i} g[src[e]] + g[i]) + bias)
template<int F>
__global__ __launch_bounds__(256) void agg_kernel(const float* __restrict__ g,
    const int* __restrict__ rowp, const int* __restrict__ esrc,
    const float* __restrict__ dis, const float* __restrict__ bias,
    float* __restrict__ out, int n){
  constexpr int V = F / 64;   // floats per lane (4 for F=256, 2 for F=128)
  int node = (int)((blockIdx.x * (size_t)blockDim.x + threadIdx.x) >> 6);
  int lane = threadIdx.x & 63;
  if(node >= n) return;
  float acc[V];
  {
    const float* gp = g + (size_t)node * F + lane * V;
    #pragma unroll
    for(int v = 0; v < V; v++) acc[v] = gp[v];     // self-loop term
  }
  int s = rowp[node], e = rowp[node + 1];
  for(int k = s; k < e; k++){
    int src = esrc[k];
    const float* gp = g + (size_t)src * F + lane * V;
    #pragma unroll
    for(int v = 0; v < V; v++) acc[v] += gp[v];
  }
  float d = dis[node];
  float* op = out + (size_t)node * F + lane * V;
  #pragma unroll
  for(int v = 0; v < V; v++){
    float r = fmaf(d, acc[v], bias[lane * V + v]);
    op[v] = fmaxf(r, 0.0f);
  }
}

// ---------------- launch ----------------

extern "C" void kernel_launch(void* const* d_in, const int* in_sizes, int n_in,
                              void* d_out, int out_size, void* d_ws, size_t ws_size,
                              hipStream_t stream){
  const float* x  = (const float*)d_in[0];
  const int*   ei = (const int*)d_in[1];       // int inputs arrive as int32
  const float* W1 = (const float*)d_in[2];
  const float* b1 = (const float*)d_in[3];
  const float* W2 = (const float*)d_in[4];
  const float* b2 = (const float*)d_in[5];
  const float* Wl = (const float*)d_in[6];
  const float* bl = (const float*)d_in[7];
  float* out = (float*)d_out;
  const int N = N_NODES;
  const int E = in_sizes[1] / 2;
  const int IN_C = 256, HID = 256, OUT_C = 128;

  char* w = (char*)d_ws;
  size_t off = 0;
  auto take = [&](size_t bytes) -> void* {
    void* p = w + off;
    off = (off + bytes + 255) & ~(size_t)255;
    return p;
  };
  int*   degi = (int*)  take((size_t)N * 4);
  float* dis  = (float*)take((size_t)N * 4);
  int*   rowp = (int*)  take((size_t)(N + 1) * 4);
  int*   woff = (int*)  take((size_t)N * 4);
  int*   esrc = (int*)  take((size_t)E * 4);
  float* bufA = (float*)take((size_t)N * 256 * 4);   // h/g buffer (GEMM out)
  float* bufB = (float*)take((size_t)N * 256 * 4);   // relu(agg) buffer

  hipMemsetAsync(degi, 0, (size_t)N * 4, stream);
  hipMemsetAsync(woff, 0, (size_t)N * 4, stream);

  count_kernel  <<<(E + 255) / 256, 256, 0, stream>>>(ei, degi, E);
  dis_kernel    <<<(N + 255) / 256, 256, 0, stream>>>(degi, dis, N);
  scan_kernel   <<<1, 1024, 0, stream>>>(degi, rowp, N);
  scatter_kernel<<<(E + 255) / 256, 256, 0, stream>>>(ei, woff, rowp, esrc, E);

  // Layer 1: g1 = dis * (x @ W1)  -> agg -> relu
  {
    dim3 grid((N + 63) / 64, HID / 64);
    gemm_kernel<true, false><<<grid, 256, 0, stream>>>(x, W1, bufA, dis, nullptr, N, IN_C, HID);
    agg_kernel<256><<<(N + 3) / 4, 256, 0, stream>>>(bufA, rowp, esrc, dis, b1, bufB, N);
  }
  // Layer 2: g2 = dis * (r1 @ W2) -> agg -> relu
  {
    dim3 grid((N + 63) / 64, OUT_C / 64);
    gemm_kernel<true, false><<<grid, 256, 0, stream>>>(bufB, W2, bufA, dis, nullptr, N, HID, OUT_C);
    agg_kernel<128><<<(N + 3) / 4, 256, 0, stream>>>(bufA, rowp, esrc, dis, b2, bufB, N);
  }
  // Final linear: out = r2 @ Wl + bl
  {
    dim3 grid((N + 63) / 64, OUT_C / 64);
    gemm_kernel<false, true><<<grid, 256, 0, stream>>>(bufB, Wl, out, nullptr, bl, N, OUT_C, OUT_C);
  }
}

// Round 3
// 486.922 us; speedup vs baseline: 1.1455x; 1.1455x over previous
//
#include <hip/hip_runtime.h>

#define N_NODES 50000

typedef __attribute__((ext_vector_type(8))) short short8v;  // 8 bf16 = 4 VGPRs
typedef __attribute__((ext_vector_type(4))) float f32x4;

__device__ __forceinline__ unsigned short f2bf(float f){
  unsigned int u = __builtin_bit_cast(unsigned int, f);
  u += 0x7FFFu + ((u >> 16) & 1u);          // RNE
  return (unsigned short)(u >> 16);
}
__device__ __forceinline__ float bf_lo(unsigned int packed){   // low bf16 of a uint
  return __builtin_bit_cast(float, packed << 16);
}
__device__ __forceinline__ float bf_hi(unsigned int packed){   // high bf16 of a uint
  return __builtin_bit_cast(float, packed & 0xFFFF0000u);
}
__device__ __forceinline__ unsigned int pack_bf2(float lo, float hi){
  return (unsigned int)f2bf(lo) | ((unsigned int)f2bf(hi) << 16);
}

// ---------------- degree / CSR construction ----------------

__global__ void count_kernel(const int* __restrict__ ei, int* __restrict__ degi, int E){
  int e = blockIdx.x * blockDim.x + threadIdx.x;
  if(e < E) atomicAdd(&degi[ei[(size_t)E + e]], 1);
}

__global__ void dis_kernel(const int* __restrict__ degi, float* __restrict__ dis, int n){
  int i = blockIdx.x * blockDim.x + threadIdx.x;
  if(i < n) dis[i] = rsqrtf((float)(degi[i] + 1));   // +1 self-loop
}

__global__ __launch_bounds__(1024) void scan_kernel(const int* __restrict__ cnt,
                                                    int* __restrict__ row_ptr, int n){
  __shared__ int sdata[1024];
  __shared__ int carry;
  int tid = threadIdx.x;
  if(tid == 0) carry = 0;
  __syncthreads();
  for(int base = 0; base < n; base += 1024){
    int i = base + tid;
    int v = (i < n) ? cnt[i] : 0;
    sdata[tid] = v;
    __syncthreads();
    for(int off = 1; off < 1024; off <<= 1){
      int t = (tid >= off) ? sdata[tid - off] : 0;
      __syncthreads();
      if(tid >= off) sdata[tid] += t;
      __syncthreads();
    }
    if(i < n) row_ptr[i] = carry + sdata[tid] - v;   // exclusive prefix
    __syncthreads();
    if(tid == 0) carry += sdata[1023];
    __syncthreads();
  }
  if(tid == 0) row_ptr[n] = carry;
}

__global__ void scatter_kernel(const int* __restrict__ ei, int* __restrict__ woff,
                               const int* __restrict__ rowp, int* __restrict__ esrc, int E){
  int e = blockIdx.x * blockDim.x + threadIdx.x;
  if(e >= E) return;
  int s = ei[e];
  int d = ei[(size_t)E + e];
  int p = atomicAdd(&woff[d], 1);
  esrc[rowp[d] + p] = s;
}

// ---------------- fp32 -> bf16 conversions ----------------

__global__ void cvt_x_kernel(const float* __restrict__ in, unsigned short* __restrict__ out,
                             int n4){  // n4 = total/4
  int i = blockIdx.x * blockDim.x + threadIdx.x;
  if(i >= n4) return;
  float4 f = *(const float4*)(in + (size_t)i * 4);
  unsigned int lo = pack_bf2(f.x, f.y);
  unsigned int hi = pack_bf2(f.z, f.w);
  *(uint2*)(out + (size_t)i * 4) = make_uint2(lo, hi);
}

// W [K][N] fp32 -> WT [N][K] bf16
__global__ void cvt_wT_kernel(const float* __restrict__ W, unsigned short* __restrict__ WT,
                              int K, int N){
  int t = blockIdx.x * blockDim.x + threadIdx.x;
  if(t >= K * N) return;
  int k = t / N, n = t - k * N;
  WT[(size_t)n * K + k] = f2bf(W[t]);
}

// ---------------- MFMA bf16 GEMM (no LDS, direct fragments) ----------------
// C[M][Nc] = A[M][K] @ BT[Nc][K]^T ; SCALE: *= dis[row]; BIAS: += bias[col].
// grid: (Nc/64, ceil(M/64)); 256 thr = 4 waves; wave w -> rows [row0+w*16, +16).
// A/B fragments both use the same contiguous-8 k-ordering per lane-group -> the
// k-permutation cancels inside the MFMA dot product (layout-agnostic correctness).
template<bool SCALE, bool BIAS, bool OUTBF>
__global__ __launch_bounds__(256) void mfma_gemm(
    const unsigned short* __restrict__ A, const unsigned short* __restrict__ BT,
    void* __restrict__ Cv, const float* __restrict__ dis, const float* __restrict__ bias,
    int M, int K, int Nc){
  int tid  = threadIdx.x;
  int wave = tid >> 6;
  int lane = tid & 63;
  int r = lane & 15;      // row-in-tile for A, col-in-tile for B
  int g = lane >> 4;      // k-group (0..3)
  int row0 = blockIdx.y * 64 + wave * 16;
  int col0 = blockIdx.x * 64;
  int arow = row0 + r; if(arow >= M) arow = M - 1;   // clamp reads, guard writes
  const unsigned short* Ap = A + (size_t)arow * K + g * 8;
  f32x4 acc[4] = {};
  for(int k0 = 0; k0 < K; k0 += 32){
    short8v a = *(const short8v*)(Ap + k0);
    #pragma unroll
    for(int j = 0; j < 4; j++){
      short8v b = *(const short8v*)(BT + (size_t)(col0 + j * 16 + r) * K + k0 + g * 8);
      acc[j] = __builtin_amdgcn_mfma_f32_16x16x32_bf16(a, b, acc[j], 0, 0, 0);
    }
  }
  // D[row = g*4 + t][col = r]  (m89-verified C/D layout)
  #pragma unroll
  for(int t = 0; t < 4; t++){
    int rr = row0 + g * 4 + t;
    if(rr >= M) continue;
    float s = SCALE ? dis[rr] : 1.0f;
    #pragma unroll
    for(int j = 0; j < 4; j++){
      int cc = col0 + j * 16 + r;
      float v = acc[j][t] * s;
      if(BIAS) v += bias[cc];
      if(OUTBF) ((unsigned short*)Cv)[(size_t)rr * Nc + cc] = f2bf(v);
      else      ((float*)Cv)[(size_t)rr * Nc + cc] = v;
    }
  }
}

// ---------------- wave-per-node gather-sum aggregation (bf16 in/out) ----------------
// out[i] = relu(dis[i] * (sum_{e: dst==i} g[src[e]] + g[i]) + bias)
template<int F>
__global__ __launch_bounds__(256) void agg_bf16(const unsigned short* __restrict__ g,
    const int* __restrict__ rowp, const int* __restrict__ esrc,
    const float* __restrict__ dis, const float* __restrict__ bias,
    unsigned short* __restrict__ out, int n){
  constexpr int V = F / 64;   // bf16 per lane: 4 (F=256) or 2 (F=128)
  int node = (int)((blockIdx.x * (size_t)blockDim.x + threadIdx.x) >> 6);
  int lane = threadIdx.x & 63;
  if(node >= n) return;
  float acc[V];
  if(V == 4){
    uint2 u = *(const uint2*)(g + (size_t)node * F + lane * 4);
    acc[0] = bf_lo(u.x); acc[1] = bf_hi(u.x); acc[2] = bf_lo(u.y); acc[3] = bf_hi(u.y);
  }else{
    unsigned int u = *(const unsigned int*)(g + (size_t)node * F + lane * 2);
    acc[0] = bf_lo(u); acc[1] = bf_hi(u);
  }
  int s = rowp[node], e = rowp[node + 1];
  for(int k = s; k < e; k++){
    const unsigned short* sp = g + (size_t)esrc[k] * F + lane * V;
    if(V == 4){
      uint2 u = *(const uint2*)sp;
      acc[0] += bf_lo(u.x); acc[1] += bf_hi(u.x); acc[2] += bf_lo(u.y); acc[3] += bf_hi(u.y);
    }else{
      unsigned int u = *(const unsigned int*)sp;
      acc[0] += bf_lo(u); acc[1] += bf_hi(u);
    }
  }
  float d = dis[node];
  float r[V];
  #pragma unroll
  for(int v = 0; v < V; v++)
    r[v] = fmaxf(fmaf(d, acc[v], bias[lane * V + v]), 0.0f);
  if(V == 4){
    uint2 o = make_uint2(pack_bf2(r[0], r[1]), pack_bf2(r[2], r[3]));
    *(uint2*)(out + (size_t)node * F + lane * 4) = o;
  }else{
    *(unsigned int*)(out + (size_t)node * F + lane * 2) = pack_bf2(r[0], r[1]);
  }
}

// ---------------- launch ----------------

extern "C" void kernel_launch(void* const* d_in, const int* in_sizes, int n_in,
                              void* d_out, int out_size, void* d_ws, size_t ws_size,
                              hipStream_t stream){
  const float* x  = (const float*)d_in[0];
  const int*   ei = (const int*)d_in[1];
  const float* W1 = (const float*)d_in[2];
  const float* b1 = (const float*)d_in[3];
  const float* W2 = (const float*)d_in[4];
  const float* b2 = (const float*)d_in[5];
  const float* Wl = (const float*)d_in[6];
  const float* bl = (const float*)d_in[7];
  float* out = (float*)d_out;
  const int N = N_NODES;
  const int E = in_sizes[1] / 2;
  const int IN_C = 256, HID = 256, OUT_C = 128;

  char* w = (char*)d_ws;
  size_t off = 0;
  auto take = [&](size_t bytes) -> void* {
    void* p = w + off;
    off = (off + bytes + 255) & ~(size_t)255;
    return p;
  };
  int*   degi = (int*)  take((size_t)N * 4);
  float* dis  = (float*)take((size_t)N * 4);
  int*   rowp = (int*)  take((size_t)(N + 1) * 4);
  int*   woff = (int*)  take((size_t)N * 4);
  int*   esrc = (int*)  take((size_t)E * 4);
  unsigned short* xbf  = (unsigned short*)take((size_t)N * 256 * 2);
  unsigned short* bufA = (unsigned short*)take((size_t)N * 256 * 2);
  unsigned short* bufB = (unsigned short*)take((size_t)N * 256 * 2);
  unsigned short* W1T  = (unsigned short*)take((size_t)IN_C * HID * 2);
  unsigned short* W2T  = (unsigned short*)take((size_t)HID * OUT_C * 2);
  unsigned short* WlT  = (unsigned short*)take((size_t)OUT_C * OUT_C * 2);

  hipMemsetAsync(degi, 0, (size_t)N * 4, stream);
  hipMemsetAsync(woff, 0, (size_t)N * 4, stream);

  count_kernel  <<<(E + 255) / 256, 256, 0, stream>>>(ei, degi, E);
  dis_kernel    <<<(N + 255) / 256, 256, 0, stream>>>(degi, dis, N);
  scan_kernel   <<<1, 1024, 0, stream>>>(degi, rowp, N);
  scatter_kernel<<<(E + 255) / 256, 256, 0, stream>>>(ei, woff, rowp, esrc, E);

  {
    int n4 = N * IN_C / 4;
    cvt_x_kernel<<<(n4 + 255) / 256, 256, 0, stream>>>(x, xbf, n4);
    cvt_wT_kernel<<<(IN_C * HID  + 255) / 256, 256, 0, stream>>>(W1, W1T, IN_C, HID);
    cvt_wT_kernel<<<(HID * OUT_C + 255) / 256, 256, 0, stream>>>(W2, W2T, HID, OUT_C);
    cvt_wT_kernel<<<(OUT_C*OUT_C + 255) / 256, 256, 0, stream>>>(Wl, WlT, OUT_C, OUT_C);
  }

  int mblocks = (N + 63) / 64;
  // Layer 1: h1 = dis * (x @ W1) -> agg -> relu(+b1)
  mfma_gemm<true, false, true><<<dim3(HID / 64, mblocks), 256, 0, stream>>>(
      xbf, W1T, bufA, dis, nullptr, N, IN_C, HID);
  agg_bf16<256><<<(N + 3) / 4, 256, 0, stream>>>(bufA, rowp, esrc, dis, b1, bufB, N);
  // Layer 2
  mfma_gemm<true, false, true><<<dim3(OUT_C / 64, mblocks), 256, 0, stream>>>(
      bufB, W2T, bufA, dis, nullptr, N, HID, OUT_C);
  agg_bf16<128><<<(N + 3) / 4, 256, 0, stream>>>(bufA, rowp, esrc, dis, b2, bufB, N);
  // Final linear: out = r2 @ Wl + bl   (fp32 out)
  mfma_gemm<false, true, false><<<dim3(OUT_C / 64, mblocks), 256, 0, stream>>>(
      bufB, WlT, out, nullptr, bl, N, OUT_C, OUT_C);
}

// Round 5
// 339.674 us; speedup vs baseline: 1.6421x; 1.4335x over previous
//
#include <hip/hip_runtime.h>

#define N_NODES 50000

typedef __attribute__((ext_vector_type(8))) short short8v;  // 8 bf16 = 4 VGPRs
typedef __attribute__((ext_vector_type(4))) float f32x4;

__device__ __forceinline__ unsigned short f2bf(float f){
  unsigned int u = __builtin_bit_cast(unsigned int, f);
  u += 0x7FFFu + ((u >> 16) & 1u);          // RNE
  return (unsigned short)(u >> 16);
}
__device__ __forceinline__ float bf_lo(unsigned int packed){
  return __builtin_bit_cast(float, packed << 16);
}
__device__ __forceinline__ float bf_hi(unsigned int packed){
  return __builtin_bit_cast(float, packed & 0xFFFF0000u);
}
__device__ __forceinline__ unsigned int pack_bf2(float lo, float hi){
  return (unsigned int)f2bf(lo) | ((unsigned int)f2bf(hi) << 16);
}

// ---------------- degree / CSR construction ----------------

__global__ void count_kernel(const int* __restrict__ ei, int* __restrict__ degi, int E){
  int e = blockIdx.x * blockDim.x + threadIdx.x;
  if(e < E) atomicAdd(&degi[ei[(size_t)E + e]], 1);
}

// phase 1: per-block local exclusive scan (1024 elems/block) + block sums; fused dis
__global__ __launch_bounds__(1024) void scan1_kernel(const int* __restrict__ cnt,
    int* __restrict__ outp, int* __restrict__ bsum, float* __restrict__ dis, int n){
  __shared__ int sd[1024];
  int tid = threadIdx.x;
  int i = blockIdx.x * 1024 + tid;
  int v = (i < n) ? cnt[i] : 0;
  if(i < n) dis[i] = rsqrtf((float)(v + 1));       // +1 self-loop
  sd[tid] = v;
  __syncthreads();
  #pragma unroll
  for(int off = 1; off < 1024; off <<= 1){
    int t = (tid >= off) ? sd[tid - off] : 0;
    __syncthreads();
    sd[tid] += t;
    __syncthreads();
  }
  if(i < n) outp[i] = sd[tid] - v;                 // local exclusive
  if(tid == 1023) bsum[blockIdx.x] = sd[1023];
}

// phase 2: single wave scans <=64 block sums -> exclusive block offsets
__global__ void scan2_kernel(const int* __restrict__ bsum, int* __restrict__ boff, int nb){
  int tid = threadIdx.x;               // one wave of 64
  int s = (tid < nb) ? bsum[tid] : 0;
  int v = s;
  #pragma unroll
  for(int off = 1; off < 64; off <<= 1){
    int t = __shfl_up(v, off);
    if(tid >= off) v += t;
  }
  if(tid < nb) boff[tid] = v - s;
}

// phase 3: add block offsets; write rowp[n] = E (known a priori)
__global__ void scan3_kernel(int* __restrict__ outp, const int* __restrict__ boff,
                             int n, int E){
  int i = blockIdx.x * blockDim.x + threadIdx.x;
  if(i < n) outp[i] += boff[i >> 10];
  if(i == 0) outp[n] = E;
}

__global__ void scatter_kernel(const int* __restrict__ ei, int* __restrict__ woff,
                               const int* __restrict__ rowp, int* __restrict__ esrc, int E){
  int e = blockIdx.x * blockDim.x + threadIdx.x;
  if(e >= E) return;
  int s = ei[e];
  int d = ei[(size_t)E + e];
  int p = atomicAdd(&woff[d], 1);
  esrc[rowp[d] + p] = s;
}

// ---------------- fp32 -> bf16 conversions ----------------

__global__ void cvt_x_kernel(const float* __restrict__ in, unsigned short* __restrict__ out,
                             int n4){
  int i = blockIdx.x * blockDim.x + threadIdx.x;
  if(i >= n4) return;
  float4 f = *(const float4*)(in + (size_t)i * 4);
  *(uint2*)(out + (size_t)i * 4) = make_uint2(pack_bf2(f.x, f.y), pack_bf2(f.z, f.w));
}

// W [K][N] fp32 -> WT [N][K] bf16
__global__ void cvt_wT_kernel(const float* __restrict__ W, unsigned short* __restrict__ WT,
                              int K, int N){
  int t = blockIdx.x * blockDim.x + threadIdx.x;
  if(t >= K * N) return;
  int k = t / N, n = t - k * N;
  WT[(size_t)n * K + k] = f2bf(W[t]);
}

// ---------------- MFMA bf16 GEMM (no LDS, direct fragments) ----------------
// C[M][Nc] = A[M][K] @ BT[Nc][K]^T ; SCALE: *= dis[row]; BIAS: += bias[col].
template<bool SCALE, bool BIAS, bool OUTBF>
__global__ __launch_bounds__(256) void mfma_gemm(
    const unsigned short* __restrict__ A, const unsigned short* __restrict__ BT,
    void* __restrict__ Cv, const float* __restrict__ dis, const float* __restrict__ bias,
    int M, int K, int Nc){
  int tid  = threadIdx.x;
  int wave = tid >> 6;
  int lane = tid & 63;
  int r = lane & 15;      // row-in-tile for A, col-in-tile for B
  int g = lane >> 4;      // k-group (0..3)
  int row0 = blockIdx.y * 64 + wave * 16;
  int col0 = blockIdx.x * 64;
  int arow = row0 + r; if(arow >= M) arow = M - 1;   // clamp reads, guard writes
  const unsigned short* Ap = A + (size_t)arow * K + g * 8;
  f32x4 acc[4] = {};
  for(int k0 = 0; k0 < K; k0 += 32){
    short8v a = *(const short8v*)(Ap + k0);
    #pragma unroll
    for(int j = 0; j < 4; j++){
      short8v b = *(const short8v*)(BT + (size_t)(col0 + j * 16 + r) * K + k0 + g * 8);
      acc[j] = __builtin_amdgcn_mfma_f32_16x16x32_bf16(a, b, acc[j], 0, 0, 0);
    }
  }
  // D[row = g*4 + t][col = r]
  #pragma unroll
  for(int t = 0; t < 4; t++){
    int rr = row0 + g * 4 + t;
    if(rr >= M) continue;
    float s = SCALE ? dis[rr] : 1.0f;
    #pragma unroll
    for(int j = 0; j < 4; j++){
      int cc = col0 + j * 16 + r;
      float v = acc[j][t] * s;
      if(BIAS) v += bias[cc];
      if(OUTBF) ((unsigned short*)Cv)[(size_t)rr * Nc + cc] = f2bf(v);
      else      ((float*)Cv)[(size_t)rr * Nc + cc] = v;
    }
  }
}

// ---------------- wave-per-node gather-sum aggregation (bf16 in/out) ----------------
// out[i] = relu(dis[i] * (sum_{e: dst==i} g[src[e]] + g[i]) + bias)
// Edge loop unrolled x4: 4 independent gathers in flight per wave (MLP).
template<int F>
__global__ __launch_bounds__(256) void agg_bf16(const unsigned short* __restrict__ g,
    const int* __restrict__ rowp, const int* __restrict__ esrc,
    const float* __restrict__ dis, const float* __restrict__ bias,
    unsigned short* __restrict__ out, int n){
  constexpr int V = F / 64;   // bf16 per lane: 4 (F=256) or 2 (F=128)
  int node = (int)((blockIdx.x * (size_t)blockDim.x + threadIdx.x) >> 6);
  int lane = threadIdx.x & 63;
  if(node >= n) return;
  float acc[V];
  if(V == 4){
    uint2 u = *(const uint2*)(g + (size_t)node * F + lane * 4);
    acc[0] = bf_lo(u.x); acc[1] = bf_hi(u.x); acc[2] = bf_lo(u.y); acc[3] = bf_hi(u.y);
  }else{
    unsigned int u = *(const unsigned int*)(g + (size_t)node * F + lane * 2);
    acc[0] = bf_lo(u); acc[1] = bf_hi(u);
  }
  int s = rowp[node], e = rowp[node + 1];
  int k = s;
  if(V == 4){
    for(; k + 4 <= e; k += 4){
      int s0 = esrc[k], s1 = esrc[k+1], s2 = esrc[k+2], s3 = esrc[k+3];
      uint2 u0 = *(const uint2*)(g + (size_t)s0 * F + lane * 4);
      uint2 u1 = *(const uint2*)(g + (size_t)s1 * F + lane * 4);
      uint2 u2 = *(const uint2*)(g + (size_t)s2 * F + lane * 4);
      uint2 u3 = *(const uint2*)(g + (size_t)s3 * F + lane * 4);
      acc[0] += bf_lo(u0.x) + bf_lo(u1.x) + bf_lo(u2.x) + bf_lo(u3.x);
      acc[1] += bf_hi(u0.x) + bf_hi(u1.x) + bf_hi(u2.x) + bf_hi(u3.x);
      acc[2] += bf_lo(u0.y) + bf_lo(u1.y) + bf_lo(u2.y) + bf_lo(u3.y);
      acc[3] += bf_hi(u0.y) + bf_hi(u1.y) + bf_hi(u2.y) + bf_hi(u3.y);
    }
    for(; k < e; k++){
      uint2 u = *(const uint2*)(g + (size_t)esrc[k] * F + lane * 4);
      acc[0] += bf_lo(u.x); acc[1] += bf_hi(u.x); acc[2] += bf_lo(u.y); acc[3] += bf_hi(u.y);
    }
  }else{
    for(; k + 4 <= e; k += 4){
      int s0 = esrc[k], s1 = esrc[k+1], s2 = esrc[k+2], s3 = esrc[k+3];
      unsigned int u0 = *(const unsigned int*)(g + (size_t)s0 * F + lane * 2);
      unsigned int u1 = *(const unsigned int*)(g + (size_t)s1 * F + lane * 2);
      unsigned int u2 = *(const unsigned int*)(g + (size_t)s2 * F + lane * 2);
      unsigned int u3 = *(const unsigned int*)(g + (size_t)s3 * F + lane * 2);
      acc[0] += bf_lo(u0) + bf_lo(u1) + bf_lo(u2) + bf_lo(u3);
      acc[1] += bf_hi(u0) + bf_hi(u1) + bf_hi(u2) + bf_hi(u3);
    }
    for(; k < e; k++){
      unsigned int u = *(const unsigned int*)(g + (size_t)esrc[k] * F + lane * 2);
      acc[0] += bf_lo(u); acc[1] += bf_hi(u);
    }
  }
  float d = dis[node];
  float r[V];
  #pragma unroll
  for(int v = 0; v < V; v++)
    r[v] = fmaxf(fmaf(d, acc[v], bias[lane * V + v]), 0.0f);
  if(V == 4){
    *(uint2*)(out + (size_t)node * F + lane * 4) =
        make_uint2(pack_bf2(r[0], r[1]), pack_bf2(r[2], r[3]));
  }else{
    *(unsigned int*)(out + (size_t)node * F + lane * 2) = pack_bf2(r[0], r[1]);
  }
}

// ---------------- launch ----------------

extern "C" void kernel_launch(void* const* d_in, const int* in_sizes, int n_in,
                              void* d_out, int out_size, void* d_ws, size_t ws_size,
                              hipStream_t stream){
  const float* x  = (const float*)d_in[0];
  const int*   ei = (const int*)d_in[1];
  const float* W1 = (const float*)d_in[2];
  const float* b1 = (const float*)d_in[3];
  const float* W2 = (const float*)d_in[4];
  const float* b2 = (const float*)d_in[5];
  const float* Wl = (const float*)d_in[6];
  const float* bl = (const float*)d_in[7];
  float* out = (float*)d_out;
  const int N = N_NODES;
  const int E = in_sizes[1] / 2;
  const int IN_C = 256, HID = 256, OUT_C = 128;

  char* w = (char*)d_ws;
  size_t off = 0;
  auto take = [&](size_t bytes) -> void* {
    void* p = w + off;
    off = (off + bytes + 255) & ~(size_t)255;
    return p;
  };
  // degi and woff in ONE allocation so a single memset covers both exactly
  // (take() pads to 256B; a merged memset over two takes left woff's tail
  //  holding 0xAA poison -> scatter OOB -> round-4 crash)
  int*   degi = (int*)  take((size_t)N * 2 * 4);
  int*   woff = degi + N;
  float* dis  = (float*)take((size_t)N * 4);
  int*   rowp = (int*)  take((size_t)(N + 1) * 4);
  int*   bsum = (int*)  take(64 * 4);
  int*   boff = (int*)  take(64 * 4);
  int*   esrc = (int*)  take((size_t)E * 4);
  unsigned short* xbf  = (unsigned short*)take((size_t)N * 256 * 2);
  unsigned short* bufA = (unsigned short*)take((size_t)N * 256 * 2);
  unsigned short* bufB = (unsigned short*)take((size_t)N * 256 * 2);
  unsigned short* W1T  = (unsigned short*)take((size_t)IN_C * HID * 2);
  unsigned short* W2T  = (unsigned short*)take((size_t)HID * OUT_C * 2);
  unsigned short* WlT  = (unsigned short*)take((size_t)OUT_C * OUT_C * 2);

  hipMemsetAsync(degi, 0, (size_t)N * 2 * 4, stream);   // degi + woff exactly

  int nb = (N + 1023) / 1024;                       // 49
  count_kernel  <<<(E + 255) / 256, 256, 0, stream>>>(ei, degi, E);
  scan1_kernel  <<<nb, 1024, 0, stream>>>(degi, rowp, bsum, dis, N);
  scan2_kernel  <<<1, 64, 0, stream>>>(bsum, boff, nb);
  scan3_kernel  <<<(N + 255) / 256, 256, 0, stream>>>(rowp, boff, N, E);
  scatter_kernel<<<(E + 255) / 256, 256, 0, stream>>>(ei, woff, rowp, esrc, E);

  {
    int n4 = N * IN_C / 4;
    cvt_x_kernel<<<(n4 + 255) / 256, 256, 0, stream>>>(x, xbf, n4);
    cvt_wT_kernel<<<(IN_C * HID  + 255) / 256, 256, 0, stream>>>(W1, W1T, IN_C, HID);
    cvt_wT_kernel<<<(HID * OUT_C + 255) / 256, 256, 0, stream>>>(W2, W2T, HID, OUT_C);
    cvt_wT_kernel<<<(OUT_C*OUT_C + 255) / 256, 256, 0, stream>>>(Wl, WlT, OUT_C, OUT_C);
  }

  int mblocks = (N + 63) / 64;
  // Layer 1: h1 = dis * (x @ W1) -> agg -> relu(+b1)
  mfma_gemm<true, false, true><<<dim3(HID / 64, mblocks), 256, 0, stream>>>(
      xbf, W1T, bufA, dis, nullptr, N, IN_C, HID);
  agg_bf16<256><<<(N + 3) / 4, 256, 0, stream>>>(bufA, rowp, esrc, dis, b1, bufB, N);
  // Layer 2
  mfma_gemm<true, false, true><<<dim3(OUT_C / 64, mblocks), 256, 0, stream>>>(
      bufB, W2T, bufA, dis, nullptr, N, HID, OUT_C);
  agg_bf16<128><<<(N + 3) / 4, 256, 0, stream>>>(bufA, rowp, esrc, dis, b2, bufB, N);
  // Final linear: out = r2 @ Wl + bl   (fp32 out)
  mfma_gemm<false, true, false><<<dim3(OUT_C / 64, mblocks), 256, 0, stream>>>(
      bufB, WlT, out, nullptr, bl, N, OUT_C, OUT_C);
}

// Round 6
// 257.665 us; speedup vs baseline: 2.1648x; 1.3183x over previous
//
#include <hip/hip_runtime.h>

#define N_NODES 50000

typedef __attribute__((ext_vector_type(8))) short short8v;  // 8 bf16 = 4 VGPRs
typedef __attribute__((ext_vector_type(4))) float f32x4;

__device__ __forceinline__ unsigned short f2bf(float f){
  unsigned int u = __builtin_bit_cast(unsigned int, f);
  u += 0x7FFFu + ((u >> 16) & 1u);          // RNE
  return (unsigned short)(u >> 16);
}
__device__ __forceinline__ float bf_lo(unsigned int packed){
  return __builtin_bit_cast(float, packed << 16);
}
__device__ __forceinline__ float bf_hi(unsigned int packed){
  return __builtin_bit_cast(float, packed & 0xFFFF0000u);
}
__device__ __forceinline__ unsigned int pack_bf2(float lo, float hi){
  return (unsigned int)f2bf(lo) | ((unsigned int)f2bf(hi) << 16);
}

// ---------------- degree / CSR construction ----------------

__global__ void count_kernel(const int* __restrict__ ei, int* __restrict__ degi, int E){
  int e = blockIdx.x * blockDim.x + threadIdx.x;
  if(e < E) atomicAdd(&degi[ei[(size_t)E + e]], 1);
}

__global__ __launch_bounds__(1024) void scan1_kernel(const int* __restrict__ cnt,
    int* __restrict__ outp, int* __restrict__ bsum, float* __restrict__ dis, int n){
  __shared__ int sd[1024];
  int tid = threadIdx.x;
  int i = blockIdx.x * 1024 + tid;
  int v = (i < n) ? cnt[i] : 0;
  if(i < n) dis[i] = rsqrtf((float)(v + 1));       // +1 self-loop
  sd[tid] = v;
  __syncthreads();
  #pragma unroll
  for(int off = 1; off < 1024; off <<= 1){
    int t = (tid >= off) ? sd[tid - off] : 0;
    __syncthreads();
    sd[tid] += t;
    __syncthreads();
  }
  if(i < n) outp[i] = sd[tid] - v;                 // local exclusive
  if(tid == 1023) bsum[blockIdx.x] = sd[1023];
}

__global__ void scan2_kernel(const int* __restrict__ bsum, int* __restrict__ boff, int nb){
  int tid = threadIdx.x;               // one wave of 64
  int s = (tid < nb) ? bsum[tid] : 0;
  int v = s;
  #pragma unroll
  for(int off = 1; off < 64; off <<= 1){
    int t = __shfl_up(v, off);
    if(tid >= off) v += t;
  }
  if(tid < nb) boff[tid] = v - s;
}

__global__ void scan3_kernel(int* __restrict__ outp, const int* __restrict__ boff,
                             int n, int E){
  int i = blockIdx.x * blockDim.x + threadIdx.x;
  if(i < n) outp[i] += boff[i >> 10];
  if(i == 0) outp[n] = E;
}

__global__ void scatter_kernel(const int* __restrict__ ei, int* __restrict__ woff,
                               const int* __restrict__ rowp, int* __restrict__ esrc, int E){
  int e = blockIdx.x * blockDim.x + threadIdx.x;
  if(e >= E) return;
  int s = ei[e];
  int d = ei[(size_t)E + e];
  int p = atomicAdd(&woff[d], 1);
  esrc[rowp[d] + p] = s;
}

// ---------------- fp32 -> bf16 conversions ----------------

__global__ void cvt_x_kernel(const float* __restrict__ in, unsigned short* __restrict__ out,
                             int n4){
  int i = blockIdx.x * blockDim.x + threadIdx.x;
  if(i >= n4) return;
  float4 f = *(const float4*)(in + (size_t)i * 4);
  *(uint2*)(out + (size_t)i * 4) = make_uint2(pack_bf2(f.x, f.y), pack_bf2(f.z, f.w));
}

// W [K][N] fp32 -> WT [N][K] bf16
__global__ void cvt_wT_kernel(const float* __restrict__ W, unsigned short* __restrict__ WT,
                              int K, int N){
  int t = blockIdx.x * blockDim.x + threadIdx.x;
  if(t >= K * N) return;
  int k = t / N, n = t - k * N;
  WT[(size_t)n * K + k] = f2bf(W[t]);
}

// ---------------- MFMA bf16 GEMM v2: LDS-staged B, templated K ----------------
// C[M][Nc] = A[M][K] @ BT[Nc][K]^T ; SCALE: *= dis[row]; BIAS: += bias[col].
// Tile: BM=128 (4 waves x 32 rows), BN=64. B panel [64][K] staged in padded LDS
// (row stride K+8 bf16 = 528B for K=256 -> read bank = 4*((r+g)%8), conflict-free).
// 1-D grid, col-tile fastest + bijective XCD chunk remap (m204): blocks sharing
// an A-tile land on the same XCD -> A fetched once.
template<int K, bool SCALE, bool BIAS, bool OUTBF>
__global__ __launch_bounds__(256) void mfma_gemm2(
    const unsigned short* __restrict__ A, const unsigned short* __restrict__ BT,
    void* __restrict__ Cv, const float* __restrict__ dis, const float* __restrict__ bias,
    int M, int Nc, int nMt, int nCt){
  __shared__ unsigned short Bs[64][K + 8];
  // bijective XCD remap
  int nwg = nMt * nCt;
  int q = nwg >> 3, r8 = nwg & 7;
  int xcd = blockIdx.x & 7, idx = blockIdx.x >> 3;
  int wgid = (xcd < r8 ? xcd * (q + 1) : r8 * (q + 1) + (xcd - r8) * q) + idx;
  int mt = wgid / nCt, ct = wgid - mt * nCt;
  int col0 = ct * 64;

  // stage B panel [64][K] -> LDS (256 threads, 16B chunks)
  constexpr int SLOTS = K / 8;                 // 16B slots per row
  #pragma unroll
  for(int t = 0; t < K / 32; t++){
    int ch = threadIdx.x + t * 256;
    int c  = ch / SLOTS, s = ch - c * SLOTS;
    float4 v = *(const float4*)(BT + (size_t)(col0 + c) * K + s * 8);
    *(float4*)&Bs[c][s * 8] = v;
  }
  __syncthreads();

  int wave = threadIdx.x >> 6;
  int lane = threadIdx.x & 63;
  int r = lane & 15;      // row-in-frag (A) / col-in-frag (B)
  int g = lane >> 4;      // k-group (0..3)
  int rowW = mt * 128 + wave * 32;             // wave's 32-row band
  int ar0 = rowW + r;      if(ar0 >= M) ar0 = M - 1;   // clamp reads
  int ar1 = rowW + 16 + r; if(ar1 >= M) ar1 = M - 1;
  const unsigned short* Ap0 = A + (size_t)ar0 * K + g * 8;
  const unsigned short* Ap1 = A + (size_t)ar1 * K + g * 8;

  f32x4 acc[2][4] = {};
  #pragma unroll
  for(int k0 = 0; k0 < K; k0 += 32){
    short8v a0 = *(const short8v*)(Ap0 + k0);
    short8v a1 = *(const short8v*)(Ap1 + k0);
    #pragma unroll
    for(int j = 0; j < 4; j++){
      short8v b = *(const short8v*)&Bs[j * 16 + r][k0 + g * 8];
      acc[0][j] = __builtin_amdgcn_mfma_f32_16x16x32_bf16(a0, b, acc[0][j], 0, 0, 0);
      acc[1][j] = __builtin_amdgcn_mfma_f32_16x16x32_bf16(a1, b, acc[1][j], 0, 0, 0);
    }
  }
  // D[row = g*4 + t][col = r] per 16x16 fragment
  #pragma unroll
  for(int p = 0; p < 2; p++){
    #pragma unroll
    for(int t = 0; t < 4; t++){
      int rr = rowW + p * 16 + g * 4 + t;
      if(rr >= M) continue;
      float s = SCALE ? dis[rr] : 1.0f;
      #pragma unroll
      for(int j = 0; j < 4; j++){
        int cc = col0 + j * 16 + r;
        float v = acc[p][j][t] * s;
        if(BIAS) v += bias[cc];
        if(OUTBF) ((unsigned short*)Cv)[(size_t)rr * Nc + cc] = f2bf(v);
        else      ((float*)Cv)[(size_t)rr * Nc + cc] = v;
      }
    }
  }
}

// ---------------- wave-per-node gather-sum aggregation (bf16 in/out) ----------------
template<int F>
__global__ __launch_bounds__(256) void agg_bf16(const unsigned short* __restrict__ g,
    const int* __restrict__ rowp, const int* __restrict__ esrc,
    const float* __restrict__ dis, const float* __restrict__ bias,
    unsigned short* __restrict__ out, int n){
  constexpr int V = F / 64;   // bf16 per lane: 4 (F=256) or 2 (F=128)
  int node = (int)((blockIdx.x * (size_t)blockDim.x + threadIdx.x) >> 6);
  int lane = threadIdx.x & 63;
  if(node >= n) return;
  float acc[V];
  if(V == 4){
    uint2 u = *(const uint2*)(g + (size_t)node * F + lane * 4);
    acc[0] = bf_lo(u.x); acc[1] = bf_hi(u.x); acc[2] = bf_lo(u.y); acc[3] = bf_hi(u.y);
  }else{
    unsigned int u = *(const unsigned int*)(g + (size_t)node * F + lane * 2);
    acc[0] = bf_lo(u); acc[1] = bf_hi(u);
  }
  int s = rowp[node], e = rowp[node + 1];
  int k = s;
  if(V == 4){
    for(; k + 4 <= e; k += 4){
      int s0 = esrc[k], s1 = esrc[k+1], s2 = esrc[k+2], s3 = esrc[k+3];
      uint2 u0 = *(const uint2*)(g + (size_t)s0 * F + lane * 4);
      uint2 u1 = *(const uint2*)(g + (size_t)s1 * F + lane * 4);
      uint2 u2 = *(const uint2*)(g + (size_t)s2 * F + lane * 4);
      uint2 u3 = *(const uint2*)(g + (size_t)s3 * F + lane * 4);
      acc[0] += bf_lo(u0.x) + bf_lo(u1.x) + bf_lo(u2.x) + bf_lo(u3.x);
      acc[1] += bf_hi(u0.x) + bf_hi(u1.x) + bf_hi(u2.x) + bf_hi(u3.x);
      acc[2] += bf_lo(u0.y) + bf_lo(u1.y) + bf_lo(u2.y) + bf_lo(u3.y);
      acc[3] += bf_hi(u0.y) + bf_hi(u1.y) + bf_hi(u2.y) + bf_hi(u3.y);
    }
    for(; k < e; k++){
      uint2 u = *(const uint2*)(g + (size_t)esrc[k] * F + lane * 4);
      acc[0] += bf_lo(u.x); acc[1] += bf_hi(u.x); acc[2] += bf_lo(u.y); acc[3] += bf_hi(u.y);
    }
  }else{
    for(; k + 4 <= e; k += 4){
      int s0 = esrc[k], s1 = esrc[k+1], s2 = esrc[k+2], s3 = esrc[k+3];
      unsigned int u0 = *(const unsigned int*)(g + (size_t)s0 * F + lane * 2);
      unsigned int u1 = *(const unsigned int*)(g + (size_t)s1 * F + lane * 2);
      unsigned int u2 = *(const unsigned int*)(g + (size_t)s2 * F + lane * 2);
      unsigned int u3 = *(const unsigned int*)(g + (size_t)s3 * F + lane * 2);
      acc[0] += bf_lo(u0) + bf_lo(u1) + bf_lo(u2) + bf_lo(u3);
      acc[1] += bf_hi(u0) + bf_hi(u1) + bf_hi(u2) + bf_hi(u3);
    }
    for(; k < e; k++){
      unsigned int u = *(const unsigned int*)(g + (size_t)esrc[k] * F + lane * 2);
      acc[0] += bf_lo(u); acc[1] += bf_hi(u);
    }
  }
  float d = dis[node];
  float r[V];
  #pragma unroll
  for(int v = 0; v < V; v++)
    r[v] = fmaxf(fmaf(d, acc[v], bias[lane * V + v]), 0.0f);
  if(V == 4){
    *(uint2*)(out + (size_t)node * F + lane * 4) =
        make_uint2(pack_bf2(r[0], r[1]), pack_bf2(r[2], r[3]));
  }else{
    *(unsigned int*)(out + (size_t)node * F + lane * 2) = pack_bf2(r[0], r[1]);
  }
}

// ---------------- launch ----------------

extern "C" void kernel_launch(void* const* d_in, const int* in_sizes, int n_in,
                              void* d_out, int out_size, void* d_ws, size_t ws_size,
                              hipStream_t stream){
  const float* x  = (const float*)d_in[0];
  const int*   ei = (const int*)d_in[1];
  const float* W1 = (const float*)d_in[2];
  const float* b1 = (const float*)d_in[3];
  const float* W2 = (const float*)d_in[4];
  const float* b2 = (const float*)d_in[5];
  const float* Wl = (const float*)d_in[6];
  const float* bl = (const float*)d_in[7];
  float* out = (float*)d_out;
  const int N = N_NODES;
  const int E = in_sizes[1] / 2;
  const int IN_C = 256, HID = 256, OUT_C = 128;

  char* w = (char*)d_ws;
  size_t off = 0;
  auto take = [&](size_t bytes) -> void* {
    void* p = w + off;
    off = (off + bytes + 255) & ~(size_t)255;
    return p;
  };
  // degi+woff in ONE allocation so one memset covers both exactly (round-4 lesson)
  int*   degi = (int*)  take((size_t)N * 2 * 4);
  int*   woff = degi + N;
  float* dis  = (float*)take((size_t)N * 4);
  int*   rowp = (int*)  take((size_t)(N + 1) * 4);
  int*   bsum = (int*)  take(64 * 4);
  int*   boff = (int*)  take(64 * 4);
  int*   esrc = (int*)  take((size_t)E * 4);
  unsigned short* xbf  = (unsigned short*)take((size_t)N * 256 * 2);
  unsigned short* bufA = (unsigned short*)take((size_t)N * 256 * 2);
  unsigned short* bufB = (unsigned short*)take((size_t)N * 256 * 2);
  unsigned short* W1T  = (unsigned short*)take((size_t)IN_C * HID * 2);
  unsigned short* W2T  = (unsigned short*)take((size_t)HID * OUT_C * 2);
  unsigned short* WlT  = (unsigned short*)take((size_t)OUT_C * OUT_C * 2);

  hipMemsetAsync(degi, 0, (size_t)N * 2 * 4, stream);

  int nb = (N + 1023) / 1024;                       // 49
  count_kernel  <<<(E + 255) / 256, 256, 0, stream>>>(ei, degi, E);
  scan1_kernel  <<<nb, 1024, 0, stream>>>(degi, rowp, bsum, dis, N);
  scan2_kernel  <<<1, 64, 0, stream>>>(bsum, boff, nb);
  scan3_kernel  <<<(N + 255) / 256, 256, 0, stream>>>(rowp, boff, N, E);
  scatter_kernel<<<(E + 255) / 256, 256, 0, stream>>>(ei, woff, rowp, esrc, E);

  {
    int n4 = N * IN_C / 4;
    cvt_x_kernel<<<(n4 + 255) / 256, 256, 0, stream>>>(x, xbf, n4);
    cvt_wT_kernel<<<(IN_C * HID  + 255) / 256, 256, 0, stream>>>(W1, W1T, IN_C, HID);
    cvt_wT_kernel<<<(HID * OUT_C + 255) / 256, 256, 0, stream>>>(W2, W2T, HID, OUT_C);
    cvt_wT_kernel<<<(OUT_C*OUT_C + 255) / 256, 256, 0, stream>>>(Wl, WlT, OUT_C, OUT_C);
  }

  int nMt = (N + 127) / 128;                        // 391
  // Layer 1: h1 = dis * (x @ W1) -> agg -> relu(+b1)
  mfma_gemm2<256, true, false, true><<<nMt * (HID / 64), 256, 0, stream>>>(
      xbf, W1T, bufA, dis, nullptr, N, HID, nMt, HID / 64);
  agg_bf16<256><<<(N + 3) / 4, 256, 0, stream>>>(bufA, rowp, esrc, dis, b1, bufB, N);
  // Layer 2
  mfma_gemm2<256, true, false, true><<<nMt * (OUT_C / 64), 256, 0, stream>>>(
      bufB, W2T, bufA, dis, nullptr, N, OUT_C, nMt, OUT_C / 64);
  agg_bf16<128><<<(N + 3) / 4, 256, 0, stream>>>(bufA, rowp, esrc, dis, b2, bufB, N);
  // Final linear: out = r2 @ Wl + bl   (fp32 out)
  mfma_gemm2<128, false, true, false><<<nMt * (OUT_C / 64), 256, 0, stream>>>(
      bufB, WlT, out, nullptr, bl, N, OUT_C, nMt, OUT_C / 64);
}

// Round 8
// 247.537 us; speedup vs baseline: 2.2533x; 1.0409x over previous
//
#include <hip/hip_runtime.h>

#define N_NODES 50000

typedef __attribute__((ext_vector_type(8))) short short8v;  // 8 bf16 = 4 VGPRs
typedef __attribute__((ext_vector_type(4))) float f32x4;

__device__ __forceinline__ unsigned short f2bf(float f){
  unsigned int u = __builtin_bit_cast(unsigned int, f);
  u += 0x7FFFu + ((u >> 16) & 1u);          // RNE
  return (unsigned short)(u >> 16);
}
__device__ __forceinline__ float bf_lo(unsigned int packed){
  return __builtin_bit_cast(float, packed << 16);
}
__device__ __forceinline__ float bf_hi(unsigned int packed){
  return __builtin_bit_cast(float, packed & 0xFFFF0000u);
}
__device__ __forceinline__ unsigned int pack_bf2(float lo, float hi){
  return (unsigned int)f2bf(lo) | ((unsigned int)f2bf(hi) << 16);
}
__device__ __forceinline__ void acc_u4(float* acc, uint4 u){
  acc[0] += bf_lo(u.x); acc[1] += bf_hi(u.x);
  acc[2] += bf_lo(u.y); acc[3] += bf_hi(u.y);
  acc[4] += bf_lo(u.z); acc[5] += bf_hi(u.z);
  acc[6] += bf_lo(u.w); acc[7] += bf_hi(u.w);
}

// ---------------- degree / CSR construction ----------------

__global__ void count_kernel(const int* __restrict__ ei, int* __restrict__ degi, int E){
  int e = blockIdx.x * blockDim.x + threadIdx.x;
  if(e < E) atomicAdd(&degi[ei[(size_t)E + e]], 1);
}

__global__ __launch_bounds__(1024) void scan1_kernel(const int* __restrict__ cnt,
    int* __restrict__ outp, int* __restrict__ bsum, float* __restrict__ dis, int n){
  __shared__ int sd[1024];
  int tid = threadIdx.x;
  int i = blockIdx.x * 1024 + tid;
  int v = (i < n) ? cnt[i] : 0;
  if(i < n) dis[i] = rsqrtf((float)(v + 1));       // +1 self-loop
  sd[tid] = v;
  __syncthreads();
  #pragma unroll
  for(int off = 1; off < 1024; off <<= 1){
    int t = (tid >= off) ? sd[tid - off] : 0;
    __syncthreads();
    sd[tid] += t;
    __syncthreads();
  }
  if(i < n) outp[i] = sd[tid] - v;                 // local exclusive
  if(tid == 1023) bsum[blockIdx.x] = sd[1023];
}

__global__ void scan2_kernel(const int* __restrict__ bsum, int* __restrict__ boff, int nb){
  int tid = threadIdx.x;               // one wave of 64
  int s = (tid < nb) ? bsum[tid] : 0;
  int v = s;
  #pragma unroll
  for(int off = 1; off < 64; off <<= 1){
    int t = __shfl_up(v, off);
    if(tid >= off) v += t;
  }
  if(tid < nb) boff[tid] = v - s;
}

__global__ void scan3_kernel(int* __restrict__ outp, const int* __restrict__ boff,
                             int n, int E){
  int i = blockIdx.x * blockDim.x + threadIdx.x;
  if(i < n) outp[i] += boff[i >> 10];
  if(i == 0) outp[n] = E;
}

__global__ void scatter_kernel(const int* __restrict__ ei, int* __restrict__ woff,
                               const int* __restrict__ rowp, int* __restrict__ esrc, int E){
  int e = blockIdx.x * blockDim.x + threadIdx.x;
  if(e >= E) return;
  int s = ei[e];
  int d = ei[(size_t)E + e];
  int p = atomicAdd(&woff[d], 1);
  esrc[rowp[d] + p] = s;
}

// ---------------- weight transpose+cvt: W [K][N] fp32 -> WT [N][K] bf16 ----------------

__global__ void cvt_wT_kernel(const float* __restrict__ W, unsigned short* __restrict__ WT,
                              int K, int N){
  int t = blockIdx.x * blockDim.x + threadIdx.x;
  if(t >= K * N) return;
  int k = t / N, n = t - k * N;
  WT[(size_t)n * K + k] = f2bf(W[t]);
}

// ---------------- MFMA bf16 GEMM: LDS-staged B, templated K, optional fp32 A ----------------
// C[M][Nc] = A[M][K] @ BT[Nc][K]^T ; SCALE: *= dis[row]; BIAS: += bias[col].
// Tile: BM=128 (4 waves x 32 rows), BN=64. B panel [64][K] staged in padded LDS.
// 1-D grid, col-tile fastest + bijective XCD chunk remap: blocks sharing an
// A-tile land on the same XCD -> A fetched ~once.
template<int K, bool AF32, bool SCALE, bool BIAS, bool OUTBF>
__global__ __launch_bounds__(256) void mfma_gemm2(
    const void* __restrict__ Av, const unsigned short* __restrict__ BT,
    void* __restrict__ Cv, const float* __restrict__ dis, const float* __restrict__ bias,
    int M, int Nc, int nMt, int nCt){
  __shared__ unsigned short Bs[64][K + 8];
  int nwg = nMt * nCt;
  int q = nwg >> 3, r8 = nwg & 7;
  int xcd = blockIdx.x & 7, idx = blockIdx.x >> 3;
  int wgid = (xcd < r8 ? xcd * (q + 1) : r8 * (q + 1) + (xcd - r8) * q) + idx;
  int mt = wgid / nCt, ct = wgid - mt * nCt;
  int col0 = ct * 64;

  constexpr int SLOTS = K / 8;                 // 16B slots per row
  #pragma unroll
  for(int t = 0; t < K / 32; t++){
    int ch = threadIdx.x + t * 256;
    int c  = ch / SLOTS, s = ch - c * SLOTS;
    float4 v = *(const float4*)(BT + (size_t)(col0 + c) * K + s * 8);
    *(float4*)&Bs[c][s * 8] = v;
  }
  __syncthreads();

  int wave = threadIdx.x >> 6;
  int lane = threadIdx.x & 63;
  int r = lane & 15;
  int g = lane >> 4;
  int rowW = mt * 128 + wave * 32;
  int ar0 = rowW + r;      if(ar0 >= M) ar0 = M - 1;
  int ar1 = rowW + 16 + r; if(ar1 >= M) ar1 = M - 1;
  const unsigned short* Ab0; const unsigned short* Ab1;
  const float* Af0; const float* Af1;
  if(AF32){
    Af0 = (const float*)Av + (size_t)ar0 * K + g * 8;
    Af1 = (const float*)Av + (size_t)ar1 * K + g * 8;
  }else{
    Ab0 = (const unsigned short*)Av + (size_t)ar0 * K + g * 8;
    Ab1 = (const unsigned short*)Av + (size_t)ar1 * K + g * 8;
  }

  f32x4 acc[2][4] = {};
  #pragma unroll
  for(int k0 = 0; k0 < K; k0 += 32){
    short8v a0, a1;
    if(AF32){
      float4 l0 = *(const float4*)(Af0 + k0), h0 = *(const float4*)(Af0 + k0 + 4);
      float4 l1 = *(const float4*)(Af1 + k0), h1 = *(const float4*)(Af1 + k0 + 4);
      a0[0]=(short)f2bf(l0.x); a0[1]=(short)f2bf(l0.y); a0[2]=(short)f2bf(l0.z); a0[3]=(short)f2bf(l0.w);
      a0[4]=(short)f2bf(h0.x); a0[5]=(short)f2bf(h0.y); a0[6]=(short)f2bf(h0.z); a0[7]=(short)f2bf(h0.w);
      a1[0]=(short)f2bf(l1.x); a1[1]=(short)f2bf(l1.y); a1[2]=(short)f2bf(l1.z); a1[3]=(short)f2bf(l1.w);
      a1[4]=(short)f2bf(h1.x); a1[5]=(short)f2bf(h1.y); a1[6]=(short)f2bf(h1.z); a1[7]=(short)f2bf(h1.w);
    }else{
      a0 = *(const short8v*)(Ab0 + k0);
      a1 = *(const short8v*)(Ab1 + k0);
    }
    #pragma unroll
    for(int j = 0; j < 4; j++){
      short8v b = *(const short8v*)&Bs[j * 16 + r][k0 + g * 8];
      acc[0][j] = __builtin_amdgcn_mfma_f32_16x16x32_bf16(a0, b, acc[0][j], 0, 0, 0);
      acc[1][j] = __builtin_amdgcn_mfma_f32_16x16x32_bf16(a1, b, acc[1][j], 0, 0, 0);
    }
  }
  #pragma unroll
  for(int p = 0; p < 2; p++){
    #pragma unroll
    for(int t = 0; t < 4; t++){
      int rr = rowW + p * 16 + g * 4 + t;
      if(rr >= M) continue;
      float s = SCALE ? dis[rr] : 1.0f;
      #pragma unroll
      for(int j = 0; j < 4; j++){
        int cc = col0 + j * 16 + r;
        float v = acc[p][j][t] * s;
        if(BIAS) v += bias[cc];
        if(OUTBF) ((unsigned short*)Cv)[(size_t)rr * Nc + cc] = f2bf(v);
        else      ((float*)Cv)[(size_t)rr * Nc + cc] = v;
      }
    }
  }
}

// ---------------- gather-sum aggregation v2: multi-node waves, 16B/lane ----------------
// out[i] = relu(dis[i] * (sum_{e: dst==i} g[src[e]] + g[i]) + bias)
// F=256: 2 nodes/wave (32 lanes x 16B = 512B row); F=128: 4 nodes/wave.
// Block = 4 waves -> covers 4*GP nodes; grid = ceil(N / (4*GP)).
template<int F>
__global__ __launch_bounds__(256) void agg2_bf16(const unsigned short* __restrict__ g,
    const int* __restrict__ rowp, const int* __restrict__ esrc,
    const float* __restrict__ dis, const float* __restrict__ bias,
    unsigned short* __restrict__ out, int n){
  constexpr int GP  = 512 / F;    // nodes per wave
  constexpr int LPG = 64 / GP;    // lanes per node (row F*2 bytes / 16B)
  int wid  = (int)((blockIdx.x * (size_t)blockDim.x + threadIdx.x) >> 6);
  int lane = threadIdx.x & 63;
  int grp  = lane / LPG;
  int sl   = lane % LPG;
  int node = wid * GP + grp;
  bool valid = node < n;
  int nd = valid ? node : 0;
  int s = 0, e = 0;
  if(valid){ s = rowp[nd]; e = rowp[nd + 1]; }
  const unsigned short* base = g + (size_t)nd * F + sl * 8;
  float acc[8] = {};
  acc_u4(acc, *(const uint4*)base);            // self-loop term
  int k = s;
  for(; k + 4 <= e; k += 4){
    int s0 = esrc[k], s1 = esrc[k+1], s2 = esrc[k+2], s3 = esrc[k+3];
    uint4 u0 = *(const uint4*)(g + (size_t)s0 * F + sl * 8);
    uint4 u1 = *(const uint4*)(g + (size_t)s1 * F + sl * 8);
    uint4 u2 = *(const uint4*)(g + (size_t)s2 * F + sl * 8);
    uint4 u3 = *(const uint4*)(g + (size_t)s3 * F + sl * 8);
    acc_u4(acc, u0); acc_u4(acc, u1); acc_u4(acc, u2); acc_u4(acc, u3);
  }
  for(; k < e; k++)
    acc_u4(acc, *(const uint4*)(g + (size_t)esrc[k] * F + sl * 8));
  if(valid){
    float d = dis[nd];
    float r[8];
    #pragma unroll
    for(int v = 0; v < 8; v++)
      r[v] = fmaxf(fmaf(d, acc[v], bias[sl * 8 + v]), 0.0f);
    uint4 o;
    o.x = pack_bf2(r[0], r[1]); o.y = pack_bf2(r[2], r[3]);
    o.z = pack_bf2(r[4], r[5]); o.w = pack_bf2(r[6], r[7]);
    *(uint4*)(out + (size_t)nd * F + sl * 8) = o;
  }
}

// ---------------- launch ----------------

extern "C" void kernel_launch(void* const* d_in, const int* in_sizes, int n_in,
                              void* d_out, int out_size, void* d_ws, size_t ws_size,
                              hipStream_t stream){
  const float* x  = (const float*)d_in[0];
  const int*   ei = (const int*)d_in[1];
  const float* W1 = (const float*)d_in[2];
  const float* b1 = (const float*)d_in[3];
  const float* W2 = (const float*)d_in[4];
  const float* b2 = (const float*)d_in[5];
  const float* Wl = (const float*)d_in[6];
  const float* bl = (const float*)d_in[7];
  float* out = (float*)d_out;
  const int N = N_NODES;
  const int E = in_sizes[1] / 2;
  const int IN_C = 256, HID = 256, OUT_C = 128;

  char* w = (char*)d_ws;
  size_t off = 0;
  auto take = [&](size_t bytes) -> void* {
    void* p = w + off;
    off = (off + bytes + 255) & ~(size_t)255;
    return p;
  };
  // degi+woff in ONE allocation so one memset covers both exactly (round-4 lesson)
  int*   degi = (int*)  take((size_t)N * 2 * 4);
  int*   woff = degi + N;
  float* dis  = (float*)take((size_t)N * 4);
  int*   rowp = (int*)  take((size_t)(N + 1) * 4);
  int*   bsum = (int*)  take(64 * 4);
  int*   boff = (int*)  take(64 * 4);
  int*   esrc = (int*)  take((size_t)E * 4);
  unsigned short* bufA = (unsigned short*)take((size_t)N * 256 * 2);
  unsigned short* bufB = (unsigned short*)take((size_t)N * 256 * 2);
  unsigned short* W1T  = (unsigned short*)take((size_t)IN_C * HID * 2);
  unsigned short* W2T  = (unsigned short*)take((size_t)HID * OUT_C * 2);
  unsigned short* WlT  = (unsigned short*)take((size_t)OUT_C * OUT_C * 2);

  hipMemsetAsync(degi, 0, (size_t)N * 2 * 4, stream);

  int nb = (N + 1023) / 1024;                       // 49
  count_kernel  <<<(E + 255) / 256, 256, 0, stream>>>(ei, degi, E);
  scan1_kernel  <<<nb, 1024, 0, stream>>>(degi, rowp, bsum, dis, N);
  scan2_kernel  <<<1, 64, 0, stream>>>(bsum, boff, nb);
  scan3_kernel  <<<(N + 255) / 256, 256, 0, stream>>>(rowp, boff, N, E);
  scatter_kernel<<<(E + 255) / 256, 256, 0, stream>>>(ei, woff, rowp, esrc, E);

  cvt_wT_kernel<<<(IN_C * HID  + 255) / 256, 256, 0, stream>>>(W1, W1T, IN_C, HID);
  cvt_wT_kernel<<<(HID * OUT_C + 255) / 256, 256, 0, stream>>>(W2, W2T, HID, OUT_C);
  cvt_wT_kernel<<<(OUT_C*OUT_C + 255) / 256, 256, 0, stream>>>(Wl, WlT, OUT_C, OUT_C);

  int nMt = (N + 127) / 128;                        // 391
  // Layer 1: h1 = dis * (x @ W1) -> agg -> relu(+b1)   (fp32 A, cvt fused)
  mfma_gemm2<256, true, true, false, true><<<nMt * (HID / 64), 256, 0, stream>>>(
      x, W1T, bufA, dis, nullptr, N, HID, nMt, HID / 64);
  agg2_bf16<256><<<(N + 7) / 8, 256, 0, stream>>>(bufA, rowp, esrc, dis, b1, bufB, N);
  // Layer 2
  mfma_gemm2<256, false, true, false, true><<<nMt * (OUT_C / 64), 256, 0, stream>>>(
      bufB, W2T, bufA, dis, nullptr, N, OUT_C, nMt, OUT_C / 64);
  agg2_bf16<128><<<(N + 15) / 16, 256, 0, stream>>>(bufA, rowp, esrc, dis, b2, bufB, N);
  // Final linear: out = r2 @ Wl + bl   (fp32 out)
  mfma_gemm2<128, false, false, true, false><<<nMt * (OUT_C / 64), 256, 0, stream>>>(
      bufB, WlT, out, nullptr, bl, N, OUT_C, nMt, OUT_C / 64);
}

// Round 9
// 241.135 us; speedup vs baseline: 2.3132x; 1.0265x over previous
//
#include <hip/hip_runtime.h>

#define N_NODES 50000

typedef __attribute__((ext_vector_type(8))) short short8v;  // 8 bf16 = 4 VGPRs
typedef __attribute__((ext_vector_type(4))) float f32x4;

__device__ __forceinline__ unsigned short f2bf(float f){
  unsigned int u = __builtin_bit_cast(unsigned int, f);
  u += 0x7FFFu + ((u >> 16) & 1u);          // RNE (setup paths only)
  return (unsigned short)(u >> 16);
}
// HW packed cvt: lo16 = bf16(lo), hi16 = bf16(hi), RNE
__device__ __forceinline__ unsigned int cvtpk(float lo, float hi){
  unsigned int r;
  asm("v_cvt_pk_bf16_f32 %0, %1, %2" : "=v"(r) : "v"(lo), "v"(hi));
  return r;
}
__device__ __forceinline__ float bf_lo(unsigned int packed){
  return __builtin_bit_cast(float, packed << 16);
}
__device__ __forceinline__ float bf_hi(unsigned int packed){
  return __builtin_bit_cast(float, packed & 0xFFFF0000u);
}
__device__ __forceinline__ void acc_u4(float* acc, uint4 u){
  acc[0] += bf_lo(u.x); acc[1] += bf_hi(u.x);
  acc[2] += bf_lo(u.y); acc[3] += bf_hi(u.y);
  acc[4] += bf_lo(u.z); acc[5] += bf_hi(u.z);
  acc[6] += bf_lo(u.w); acc[7] += bf_hi(u.w);
}

// ---------------- fused setup: degree count + 3x weight transpose/cvt ----------------

__global__ void setup_kernel(const int* __restrict__ ei, int* __restrict__ degi, int E,
    const float* __restrict__ W1, const float* __restrict__ W2, const float* __restrict__ Wl,
    unsigned short* __restrict__ W1T, unsigned short* __restrict__ W2T,
    unsigned short* __restrict__ WlT){
  int nEb = (E + 255) >> 8;
  int b = blockIdx.x;
  if(b < nEb){
    int e = b * 256 + threadIdx.x;
    if(e < E) atomicAdd(&degi[ei[(size_t)E + e]], 1);
  }else{
    int t = (b - nEb) * 256 + threadIdx.x;
    if(t < 65536){                      // W1 [256][256] -> W1T [256][256]
      int k = t >> 8, n = t & 255;
      W1T[n * 256 + k] = f2bf(W1[t]);
    }else if(t < 98304){                // W2 [256][128] -> W2T [128][256]
      int u = t - 65536; int k = u >> 7, n = u & 127;
      W2T[n * 256 + k] = f2bf(W2[u]);
    }else if(t < 114688){               // Wl [128][128] -> WlT [128][128]
      int u = t - 98304; int k = u >> 7, n = u & 127;
      WlT[n * 128 + k] = f2bf(Wl[u]);
    }
  }
}

// ---------------- CSR construction ----------------

__global__ __launch_bounds__(1024) void scan1_kernel(const int* __restrict__ cnt,
    int* __restrict__ outp, int* __restrict__ bsum, float* __restrict__ dis, int n){
  __shared__ int sd[1024];
  int tid = threadIdx.x;
  int i = blockIdx.x * 1024 + tid;
  int v = (i < n) ? cnt[i] : 0;
  if(i < n) dis[i] = rsqrtf((float)(v + 1));       // +1 self-loop
  sd[tid] = v;
  __syncthreads();
  #pragma unroll
  for(int off = 1; off < 1024; off <<= 1){
    int t = (tid >= off) ? sd[tid - off] : 0;
    __syncthreads();
    sd[tid] += t;
    __syncthreads();
  }
  if(i < n) outp[i] = sd[tid] - v;                 // local exclusive
  if(tid == 1023) bsum[blockIdx.x] = sd[1023];
}

__global__ void scan2_kernel(const int* __restrict__ bsum, int* __restrict__ boff, int nb){
  int tid = threadIdx.x;               // one wave of 64
  int s = (tid < nb) ? bsum[tid] : 0;
  int v = s;
  #pragma unroll
  for(int off = 1; off < 64; off <<= 1){
    int t = __shfl_up(v, off);
    if(tid >= off) v += t;
  }
  if(tid < nb) boff[tid] = v - s;
}

__global__ void scan3_kernel(int* __restrict__ outp, const int* __restrict__ boff,
                             int n, int E){
  int i = blockIdx.x * blockDim.x + threadIdx.x;
  if(i < n) outp[i] += boff[i >> 10];
  if(i == 0) outp[n] = E;
}

__global__ void scatter_kernel(const int* __restrict__ ei, int* __restrict__ woff,
                               const int* __restrict__ rowp, int* __restrict__ esrc, int E){
  int e = blockIdx.x * blockDim.x + threadIdx.x;
  if(e >= E) return;
  int s = ei[e];
  int d = ei[(size_t)E + e];
  int p = atomicAdd(&woff[d], 1);
  esrc[rowp[d] + p] = s;
}

// ---------------- MFMA bf16 GEMM: LDS-staged B, templated K, optional fp32 A ----------------
// C[M][Nc] = A[M][K] @ BT[Nc][K]^T ; SCALE: *= dis[row]; BIAS: += bias[col].
// Tile: BM=128 (4 waves x 32 rows), BN=64. B panel [64][K] staged in padded LDS.
// 1-D grid, col-tile fastest + bijective XCD chunk remap.
template<int K, bool AF32, bool SCALE, bool BIAS, bool OUTBF>
__global__ __launch_bounds__(256) void mfma_gemm2(
    const void* __restrict__ Av, const unsigned short* __restrict__ BT,
    void* __restrict__ Cv, const float* __restrict__ dis, const float* __restrict__ bias,
    int M, int Nc, int nMt, int nCt){
  __shared__ unsigned short Bs[64][K + 8];
  int nwg = nMt * nCt;
  int q = nwg >> 3, r8 = nwg & 7;
  int xcd = blockIdx.x & 7, idx = blockIdx.x >> 3;
  int wgid = (xcd < r8 ? xcd * (q + 1) : r8 * (q + 1) + (xcd - r8) * q) + idx;
  int mt = wgid / nCt, ct = wgid - mt * nCt;
  int col0 = ct * 64;

  constexpr int SLOTS = K / 8;                 // 16B slots per row
  #pragma unroll
  for(int t = 0; t < K / 32; t++){
    int ch = threadIdx.x + t * 256;
    int c  = ch / SLOTS, s = ch - c * SLOTS;
    float4 v = *(const float4*)(BT + (size_t)(col0 + c) * K + s * 8);
    *(float4*)&Bs[c][s * 8] = v;
  }
  __syncthreads();

  int wave = threadIdx.x >> 6;
  int lane = threadIdx.x & 63;
  int r = lane & 15;
  int g = lane >> 4;
  int rowW = mt * 128 + wave * 32;
  int ar0 = rowW + r;      if(ar0 >= M) ar0 = M - 1;
  int ar1 = rowW + 16 + r; if(ar1 >= M) ar1 = M - 1;
  const unsigned short* Ab0; const unsigned short* Ab1;
  const float* Af0; const float* Af1;
  if(AF32){
    Af0 = (const float*)Av + (size_t)ar0 * K + g * 8;
    Af1 = (const float*)Av + (size_t)ar1 * K + g * 8;
  }else{
    Ab0 = (const unsigned short*)Av + (size_t)ar0 * K + g * 8;
    Ab1 = (const unsigned short*)Av + (size_t)ar1 * K + g * 8;
  }

  f32x4 acc[2][4] = {};
  #pragma unroll
  for(int k0 = 0; k0 < K; k0 += 32){
    short8v a0, a1;
    if(AF32){
      float4 l0 = *(const float4*)(Af0 + k0), h0 = *(const float4*)(Af0 + k0 + 4);
      float4 l1 = *(const float4*)(Af1 + k0), h1 = *(const float4*)(Af1 + k0 + 4);
      uint4 p0 = make_uint4(cvtpk(l0.x, l0.y), cvtpk(l0.z, l0.w),
                            cvtpk(h0.x, h0.y), cvtpk(h0.z, h0.w));
      uint4 p1 = make_uint4(cvtpk(l1.x, l1.y), cvtpk(l1.z, l1.w),
                            cvtpk(h1.x, h1.y), cvtpk(h1.z, h1.w));
      a0 = __builtin_bit_cast(short8v, p0);
      a1 = __builtin_bit_cast(short8v, p1);
    }else{
      a0 = *(const short8v*)(Ab0 + k0);
      a1 = *(const short8v*)(Ab1 + k0);
    }
    #pragma unroll
    for(int j = 0; j < 4; j++){
      short8v b = *(const short8v*)&Bs[j * 16 + r][k0 + g * 8];
      acc[0][j] = __builtin_amdgcn_mfma_f32_16x16x32_bf16(a0, b, acc[0][j], 0, 0, 0);
      acc[1][j] = __builtin_amdgcn_mfma_f32_16x16x32_bf16(a1, b, acc[1][j], 0, 0, 0);
    }
  }
  #pragma unroll
  for(int p = 0; p < 2; p++){
    #pragma unroll
    for(int t = 0; t < 4; t++){
      int rr = rowW + p * 16 + g * 4 + t;
      if(rr >= M) continue;
      float s = SCALE ? dis[rr] : 1.0f;
      #pragma unroll
      for(int j = 0; j < 4; j++){
        int cc = col0 + j * 16 + r;
        float v = acc[p][j][t] * s;
        if(BIAS) v += bias[cc];
        if(OUTBF) ((unsigned short*)Cv)[(size_t)rr * Nc + cc] =
                      (unsigned short)cvtpk(v, v);   // store_short keeps low 16
        else      ((float*)Cv)[(size_t)rr * Nc + cc] = v;
      }
    }
  }
}

// ---------------- gather-sum aggregation: multi-node waves, 16B/lane ----------------
// out[i] = relu(dis[i] * (sum_{e: dst==i} g[src[e]] + g[i]) + bias)
// F=256: 2 nodes/wave; F=128: 4 nodes/wave. Block = 4 waves -> 4*GP nodes.
template<int F>
__global__ __launch_bounds__(256) void agg2_bf16(const unsigned short* __restrict__ g,
    const int* __restrict__ rowp, const int* __restrict__ esrc,
    const float* __restrict__ dis, const float* __restrict__ bias,
    unsigned short* __restrict__ out, int n){
  constexpr int GP  = 512 / F;    // nodes per wave
  constexpr int LPG = 64 / GP;    // lanes per node (row F*2 bytes / 16B)
  int wid  = (int)((blockIdx.x * (size_t)blockDim.x + threadIdx.x) >> 6);
  int lane = threadIdx.x & 63;
  int grp  = lane / LPG;
  int sl   = lane % LPG;
  int node = wid * GP + grp;
  bool valid = node < n;
  int nd = valid ? node : 0;
  int s = 0, e = 0;
  if(valid){ s = rowp[nd]; e = rowp[nd + 1]; }
  const unsigned short* base = g + (size_t)nd * F + sl * 8;
  float acc[8] = {};
  acc_u4(acc, *(const uint4*)base);            // self-loop term
  int k = s;
  for(; k + 4 <= e; k += 4){
    int s0 = esrc[k], s1 = esrc[k+1], s2 = esrc[k+2], s3 = esrc[k+3];
    uint4 u0 = *(const uint4*)(g + (size_t)s0 * F + sl * 8);
    uint4 u1 = *(const uint4*)(g + (size_t)s1 * F + sl * 8);
    uint4 u2 = *(const uint4*)(g + (size_t)s2 * F + sl * 8);
    uint4 u3 = *(const uint4*)(g + (size_t)s3 * F + sl * 8);
    acc_u4(acc, u0); acc_u4(acc, u1); acc_u4(acc, u2); acc_u4(acc, u3);
  }
  for(; k < e; k++)
    acc_u4(acc, *(const uint4*)(g + (size_t)esrc[k] * F + sl * 8));
  if(valid){
    float d = dis[nd];
    float r[8];
    #pragma unroll
    for(int v = 0; v < 8; v++)
      r[v] = fmaxf(fmaf(d, acc[v], bias[sl * 8 + v]), 0.0f);
    uint4 o = make_uint4(cvtpk(r[0], r[1]), cvtpk(r[2], r[3]),
                         cvtpk(r[4], r[5]), cvtpk(r[6], r[7]));
    *(uint4*)(out + (size_t)nd * F + sl * 8) = o;
  }
}

// ---------------- launch ----------------

extern "C" void kernel_launch(void* const* d_in, const int* in_sizes, int n_in,
                              void* d_out, int out_size, void* d_ws, size_t ws_size,
                              hipStream_t stream){
  const float* x  = (const float*)d_in[0];
  const int*   ei = (const int*)d_in[1];
  const float* W1 = (const float*)d_in[2];
  const float* b1 = (const float*)d_in[3];
  const float* W2 = (const float*)d_in[4];
  const float* b2 = (const float*)d_in[5];
  const float* Wl = (const float*)d_in[6];
  const float* bl = (const float*)d_in[7];
  float* out = (float*)d_out;
  const int N = N_NODES;
  const int E = in_sizes[1] / 2;
  const int IN_C = 256, HID = 256, OUT_C = 128;

  char* w = (char*)d_ws;
  size_t off = 0;
  auto take = [&](size_t bytes) -> void* {
    void* p = w + off;
    off = (off + bytes + 255) & ~(size_t)255;
    return p;
  };
  // degi+woff in ONE allocation so one memset covers both exactly (round-4 lesson)
  int*   degi = (int*)  take((size_t)N * 2 * 4);
  int*   woff = degi + N;
  float* dis  = (float*)take((size_t)N * 4);
  int*   rowp = (int*)  take((size_t)(N + 1) * 4);
  int*   bsum = (int*)  take(64 * 4);
  int*   boff = (int*)  take(64 * 4);
  int*   esrc = (int*)  take((size_t)E * 4);
  unsigned short* bufA = (unsigned short*)take((size_t)N * 256 * 2);
  unsigned short* bufB = (unsigned short*)take((size_t)N * 256 * 2);
  unsigned short* W1T  = (unsigned short*)take((size_t)IN_C * HID * 2);
  unsigned short* W2T  = (unsigned short*)take((size_t)HID * OUT_C * 2);
  unsigned short* WlT  = (unsigned short*)take((size_t)OUT_C * OUT_C * 2);

  hipMemsetAsync(degi, 0, (size_t)N * 2 * 4, stream);

  int nEb = (E + 255) / 256;                        // 3125
  int nWb = (IN_C * HID + HID * OUT_C + OUT_C * OUT_C + 255) / 256;  // 448
  setup_kernel<<<nEb + nWb, 256, 0, stream>>>(ei, degi, E, W1, W2, Wl, W1T, W2T, WlT);

  int nb = (N + 1023) / 1024;                       // 49
  scan1_kernel  <<<nb, 1024, 0, stream>>>(degi, rowp, bsum, dis, N);
  scan2_kernel  <<<1, 64, 0, stream>>>(bsum, boff, nb);
  scan3_kernel  <<<(N + 255) / 256, 256, 0, stream>>>(rowp, boff, N, E);
  scatter_kernel<<<(E + 255) / 256, 256, 0, stream>>>(ei, woff, rowp, esrc, E);

  int nMt = (N + 127) / 128;                        // 391
  // Layer 1: h1 = dis * (x @ W1) -> agg -> relu(+b1)   (fp32 A, cvt fused via cvt_pk)
  mfma_gemm2<256, true, true, false, true><<<nMt * (HID / 64), 256, 0, stream>>>(
      x, W1T, bufA, dis, nullptr, N, HID, nMt, HID / 64);
  agg2_bf16<256><<<(N + 7) / 8, 256, 0, stream>>>(bufA, rowp, esrc, dis, b1, bufB, N);
  // Layer 2
  mfma_gemm2<256, false, true, false, true><<<nMt * (OUT_C / 64), 256, 0, stream>>>(
      bufB, W2T, bufA, dis, nullptr, N, OUT_C, nMt, OUT_C / 64);
  agg2_bf16<128><<<(N + 15) / 16, 256, 0, stream>>>(bufA, rowp, esrc, dis, b2, bufB, N);
  // Final linear: out = r2 @ Wl + bl   (fp32 out)
  mfma_gemm2<128, false, false, true, false><<<nMt * (OUT_C / 64), 256, 0, stream>>>(
      bufB, WlT, out, nullptr, bl, N, OUT_C, nMt, OUT_C / 64);
}